// Round 1
// baseline (267.380 us; speedup 1.0000x reference)
//
#include <hip/hip_runtime.h>

// Problem constants (match reference)
#define B_ 4
#define N_ 16384
#define M_ 128
#define C_ 128
#define S_ 512
#define ROW_ (3 + C_)   // 131 floats per pooled row

// ---------------------------------------------------------------------------
// Kernel A: per-box ordered compaction of in-box point indices.
// One 256-thread block per (b, m). Preserves ascending point order via
// chunked ballot prefix sums. Resolves wrap-around sampling (s % cnt) into a
// dense table resolved[bm*S + s] (-1 when the box is empty). Also writes the
// empty flag (as float 0/1 — output buffer is read back as float32).
// ---------------------------------------------------------------------------
__global__ __launch_bounds__(256) void build_idx_kernel(
    const float* __restrict__ points,   // (B, N, 3)
    const float* __restrict__ boxes,    // (B*M, 7)
    int* __restrict__ resolved,         // (B*M, S)
    float* __restrict__ flags_out)      // (B*M,)
{
    const int bm  = blockIdx.x;         // [0, B*M)
    const int b   = bm >> 7;            // / M_ (M_ == 128)
    const int tid = threadIdx.x;

    __shared__ int s_idx[S_];
    __shared__ int s_wcnt[4];

    // Box parameters (broadcast through cache; all threads same address)
    const float* bx = boxes + bm * 7;
    const float cx = bx[0], cy = bx[1], czb = bx[2];
    const float dx = bx[3], dy = bx[4], dzv = bx[5], rz = bx[6];

    // Replicate fp32 reference semantics exactly (no FMA contraction).
    const float cz   = __fadd_rn(czb, __fmul_rn(0.5f, dzv));
    const float cosa = (float)cos(-(double)rz);   // correctly-rounded fp32
    const float sina = (float)sin(-(double)rz);
    const float hdx = 0.5f * dx, hdy = 0.5f * dy, hdz = 0.5f * dzv;

    const float* pb  = points + (size_t)b * N_ * 3;
    const int lane = tid & 63;
    const int w    = tid >> 6;
    const unsigned long long lanemask = (lane == 63) ? ~0ull >> 1
                                                     : (1ull << lane) - 1ull;

    int running = 0;  // uniform across threads: total in-box points so far
    for (int base = 0; base < N_; base += 256) {
        const int i = base + tid;
        const float x = pb[i * 3 + 0];
        const float y = pb[i * 3 + 1];
        const float z = pb[i * 3 + 2];

        const float sx = __fsub_rn(x, cx);
        const float sy = __fsub_rn(y, cy);
        const float lx = __fsub_rn(__fmul_rn(sx, cosa), __fmul_rn(sy, sina));
        const float ly = __fadd_rn(__fmul_rn(sx, sina), __fmul_rn(sy, cosa));

        const bool pred =
            (fabsf(__fsub_rn(z, cz)) <= hdz) &&
            (lx > -hdx) && (lx < hdx) &&
            (ly > -hdy) && (ly < hdy);

        const unsigned long long mask = __ballot(pred);
        const int prefix = __popcll(mask & lanemask);
        if (lane == 0) s_wcnt[w] = __popcll(mask);
        __syncthreads();

        int wbase = 0, total = 0;
        #pragma unroll
        for (int j = 0; j < 4; ++j) {
            const int c = s_wcnt[j];
            if (j < w) wbase += c;
            total += c;
        }
        if (pred) {
            const int pos = running + wbase + prefix;
            if (pos < S_) s_idx[pos] = i;
        }
        running += total;
        __syncthreads();
        if (running >= S_) break;  // first S indices found; rest irrelevant
    }

    const int cnt     = running;
    const int cnt_eff = cnt < S_ ? cnt : S_;
    int* rbase = resolved + (size_t)bm * S_;
    if (cnt == 0) {
        for (int s = tid; s < S_; s += 256) rbase[s] = -1;
    } else {
        for (int s = tid; s < S_; s += 256) rbase[s] = s_idx[s % cnt_eff];
    }
    if (tid == 0) flags_out[bm] = (cnt == 0) ? 1.0f : 0.0f;
}

// ---------------------------------------------------------------------------
// Kernel B: one thread per output element. Fully coalesced stores; feature
// reads contiguous within each 512 B row (L2/L3-resident: feats = 32 MB).
// ---------------------------------------------------------------------------
__global__ __launch_bounds__(256) void gather_kernel(
    const float* __restrict__ points,   // (B, N, 3)
    const float* __restrict__ feats,    // (B, N, C)
    const int* __restrict__ resolved,   // (B*M, S)
    float* __restrict__ out)            // (B, M, S, 131)
{
    const int e = blockIdx.x * 256 + threadIdx.x;   // < 34,340,864
    const unsigned int row = (unsigned int)e / (unsigned int)ROW_;
    const int col = e - (int)row * ROW_;

    const int idx = resolved[row];
    float val = 0.0f;
    if (idx >= 0) {
        const unsigned int b = row >> 16;           // / (M_*S_) == /65536
        const size_t pbase = (size_t)b * N_ + (unsigned)idx;
        val = (col < 3) ? points[pbase * 3 + col]
                        : feats[pbase * C_ + (col - 3)];
    }
    out[e] = val;
}

extern "C" void kernel_launch(void* const* d_in, const int* in_sizes, int n_in,
                              void* d_out, int out_size, void* d_ws, size_t ws_size,
                              hipStream_t stream) {
    const float* points = (const float*)d_in[0];   // (B, N, 3)
    const float* feats  = (const float*)d_in[1];   // (B, N, C)
    const float* boxes  = (const float*)d_in[2];   // (B, M, 7)
    float* out = (float*)d_out;

    int* resolved = (int*)d_ws;                    // B*M*S ints = 1 MB
    float* flags  = out + (size_t)B_ * M_ * S_ * ROW_;

    build_idx_kernel<<<B_ * M_, 256, 0, stream>>>(points, boxes, resolved, flags);

    const int total = B_ * M_ * S_ * ROW_;         // 34,340,864 = 256 * 134,144
    gather_kernel<<<total / 256, 256, 0, stream>>>(points, feats, resolved, out);
}

// Round 3
// 223.830 us; speedup vs baseline: 1.1946x; 1.1946x over previous
//
#include <hip/hip_runtime.h>

// Problem constants (match reference)
#define B_ 4
#define N_ 16384
#define M_ 128
#define C_ 128
#define S_ 512
#define ROW_ (3 + C_)      // 131 floats per pooled row
#define NCHUNK_ 256        // 64-point chunks per box (N_/64)

typedef float f4_t __attribute__((ext_vector_type(4)));  // native vec for NT store

// ---------------------------------------------------------------------------
// Phase A: per-(box, chunk) in-box bitmask via wave ballot.
// One wave handles 16 chunks (1024 points) of one box. 8192 waves total.
// Points (786 KB) are L2-resident; this is latency-friendly parallel work.
// ---------------------------------------------------------------------------
__global__ __launch_bounds__(256) void mask_kernel(
    const float* __restrict__ points,        // (B, N, 3)
    const float* __restrict__ boxes,         // (B*M, 7)
    unsigned long long* __restrict__ masks,  // (B*M, NCHUNK_)
    int* __restrict__ cnts)                  // (B*M, NCHUNK_)
{
    const int gwave = blockIdx.x * 4 + (threadIdx.x >> 6);
    const int lane  = threadIdx.x & 63;
    const int bm    = gwave >> 4;            // 16 segments per box
    const int seg   = gwave & 15;
    const int b     = bm >> 7;               // / M_

    const float* bx = boxes + bm * 7;
    const float cx = bx[0], cy = bx[1], czb = bx[2];
    const float dx = bx[3], dy = bx[4], dzv = bx[5], rz = bx[6];
    // fp32 reference semantics: no FMA contraction; trig via double → fp32
    const float cz   = __fadd_rn(czb, __fmul_rn(0.5f, dzv));
    const float cosa = (float)cos(-(double)rz);
    const float sina = (float)sin(-(double)rz);
    const float hdx = 0.5f * dx, hdy = 0.5f * dy, hdz = 0.5f * dzv;

    const float* pb = points + (size_t)b * N_ * 3;

    #pragma unroll 4
    for (int k = 0; k < 16; ++k) {
        const int chunk = seg * 16 + k;
        const int i = chunk * 64 + lane;
        const float x = pb[i*3+0], y = pb[i*3+1], z = pb[i*3+2];
        const float sx = __fsub_rn(x, cx);
        const float sy = __fsub_rn(y, cy);
        const float lx = __fsub_rn(__fmul_rn(sx, cosa), __fmul_rn(sy, sina));
        const float ly = __fadd_rn(__fmul_rn(sx, sina), __fmul_rn(sy, cosa));
        const bool pred = (fabsf(__fsub_rn(z, cz)) <= hdz) &&
                          (lx > -hdx) && (lx < hdx) &&
                          (ly > -hdy) && (ly < hdy);
        const unsigned long long m = __ballot(pred);
        if (lane == 0) {
            masks[(size_t)bm * NCHUNK_ + chunk] = m;
            cnts [(size_t)bm * NCHUNK_ + chunk] = __popcll(m);
        }
    }
}

// ---------------------------------------------------------------------------
// Phase B: one block per box. Prefix-scan chunk counts, expand only the
// masks contributing to the first S in-box indices, resolve wrap-around
// sampling into resolved[bm][s] (-1 when empty), write empty flag.
// ---------------------------------------------------------------------------
__global__ __launch_bounds__(256) void resolve_kernel(
    const unsigned long long* __restrict__ masks,
    const int* __restrict__ cnts,
    int* __restrict__ resolved,              // (B*M, S)
    float* __restrict__ flags_out)           // (B*M,)
{
    const int bm  = blockIdx.x;
    const int tid = threadIdx.x;
    __shared__ int sc[NCHUNK_];
    __shared__ int s_idx[S_];

    const int c = cnts[(size_t)bm * NCHUNK_ + tid];
    sc[tid] = c;
    __syncthreads();
    // Hillis–Steele inclusive scan over 256 chunk counts
    for (int off = 1; off < NCHUNK_; off <<= 1) {
        const int v = (tid >= off) ? sc[tid - off] : 0;
        __syncthreads();
        sc[tid] += v;
        __syncthreads();
    }
    const int total = sc[NCHUNK_ - 1];
    const int P = sc[tid] - c;               // exclusive prefix (ordered)

    if (c > 0 && P < S_) {
        unsigned long long m = masks[(size_t)bm * NCHUNK_ + tid];
        int pos = P;
        while (m && pos < S_) {
            const int bit = __ffsll((unsigned long long)m) - 1;
            m &= m - 1;
            s_idx[pos++] = tid * 64 + bit;   // ascending point order preserved
        }
    }
    __syncthreads();

    const int cnt_eff = total < S_ ? total : S_;
    int* rbase = resolved + (size_t)bm * S_;
    if (total == 0) {
        for (int s = tid; s < S_; s += 256) rbase[s] = -1;
    } else {
        for (int s = tid; s < S_; s += 256) rbase[s] = s_idx[s % cnt_eff];
    }
    if (tid == 0) flags_out[bm] = (total == 0) ? 1.0f : 0.0f;
}

// ---------------------------------------------------------------------------
// Gather: one float4 (16 B) non-temporal store per thread. A 4-element chunk
// straddles a 131-float row boundary only when col>=128 (~3% of threads).
// NT stores keep the 32 MB feature set resident in L2 under the 131 MB
// output stream.
// ---------------------------------------------------------------------------
__global__ __launch_bounds__(256) void gather_kernel(
    const float* __restrict__ points,        // (B, N, 3)
    const float* __restrict__ feats,         // (B, N, C)
    const int* __restrict__ resolved,        // (B*M, S)
    float* __restrict__ out)                 // (B, M, S, 131)
{
    const int t = blockIdx.x * 256 + threadIdx.x;    // float4 index
    const int e = t * 4;                             // element index
    const unsigned row = (unsigned)e / (unsigned)ROW_;
    const int col = e - (int)row * ROW_;

    f4_t v = {0.f, 0.f, 0.f, 0.f};
    if (col < ROW_ - 3) {                    // col <= 127: single row
        const int idx = resolved[row];
        if (idx >= 0) {
            const unsigned b = row >> 16;    // / (M_*S_)
            const size_t pbase = (size_t)b * N_ + (unsigned)idx;
            if (col >= 3) {                  // all-features fast path
                const float* f = feats + pbase * C_ + (col - 3);
                v.x = f[0]; v.y = f[1]; v.z = f[2]; v.w = f[3];
            } else {                         // mixed xyz/features head
                const float* pp = points + pbase * 3;
                const float* f  = feats + pbase * C_;
                float tmp[4];
                #pragma unroll
                for (int j = 0; j < 4; ++j) {
                    const int cc = col + j;
                    tmp[j] = (cc < 3) ? pp[cc] : f[cc - 3];
                }
                v.x = tmp[0]; v.y = tmp[1]; v.z = tmp[2]; v.w = tmp[3];
            }
        }
    } else {                                 // straddles into next row
        float tmp[4];
        #pragma unroll
        for (int j = 0; j < 4; ++j) {
            int cc = col + j;
            unsigned rr = row;
            if (cc >= ROW_) { cc -= ROW_; rr += 1; }
            const int idx = resolved[rr];
            float val = 0.f;
            if (idx >= 0) {
                const unsigned b = rr >> 16;
                const size_t pbase = (size_t)b * N_ + (unsigned)idx;
                val = (cc < 3) ? points[pbase * 3 + cc]
                               : feats[pbase * C_ + (cc - 3)];
            }
            tmp[j] = val;
        }
        v.x = tmp[0]; v.y = tmp[1]; v.z = tmp[2]; v.w = tmp[3];
    }
    __builtin_nontemporal_store(v, (f4_t*)out + t);
}

extern "C" void kernel_launch(void* const* d_in, const int* in_sizes, int n_in,
                              void* d_out, int out_size, void* d_ws, size_t ws_size,
                              hipStream_t stream) {
    const float* points = (const float*)d_in[0];   // (B, N, 3)
    const float* feats  = (const float*)d_in[1];   // (B, N, C)
    const float* boxes  = (const float*)d_in[2];   // (B, M, 7)
    float* out = (float*)d_out;

    // Workspace layout (2.5 MB total)
    int* resolved = (int*)d_ws;                                    // 1 MB
    unsigned long long* masks =
        (unsigned long long*)((char*)d_ws + (size_t)B_*M_*S_*4);   // 1 MB
    int* cnts = (int*)((char*)masks + (size_t)B_*M_*NCHUNK_*8);    // 0.5 MB

    float* flags = out + (size_t)B_ * M_ * S_ * ROW_;

    // Phase A: 512 boxes × 16 wave-segments = 8192 waves = 2048 blocks
    mask_kernel<<<B_ * M_ * 16 / 4, 256, 0, stream>>>(points, boxes, masks, cnts);
    // Phase B: one block per box
    resolve_kernel<<<B_ * M_, 256, 0, stream>>>(masks, cnts, resolved, flags);
    // Gather: 34,340,864 elements / 4 per thread / 256 per block = 33,536
    gather_kernel<<<(B_ * M_ * S_ * ROW_) / 4 / 256, 256, 0, stream>>>(
        points, feats, resolved, out);
}

// Round 4
// 201.196 us; speedup vs baseline: 1.3290x; 1.1125x over previous
//
#include <hip/hip_runtime.h>

// Problem constants (match reference)
#define B_ 4
#define N_ 16384
#define M_ 128
#define C_ 128
#define S_ 512
#define ROW_ (3 + C_)      // 131 floats per pooled row
#define NCHUNK_ 256        // 64-point chunks per box (N_/64)
#define TILE_ 128          // unique rows staged in LDS per box
#define RSTR_ 132          // LDS row stride (feats 0..127, xyz 128..130, pad)

typedef float f4_t __attribute__((ext_vector_type(4)));

// ---------------------------------------------------------------------------
// Phase A: per-(box, chunk) in-box bitmask via wave ballot.
// One wave handles 16 chunks (1024 points) of one box. 8192 waves total.
// ---------------------------------------------------------------------------
__global__ __launch_bounds__(256) void mask_kernel(
    const float* __restrict__ points,        // (B, N, 3)
    const float* __restrict__ boxes,         // (B*M, 7)
    unsigned long long* __restrict__ masks,  // (B*M, NCHUNK_)
    int* __restrict__ cnts)                  // (B*M, NCHUNK_)
{
    const int gwave = blockIdx.x * 4 + (threadIdx.x >> 6);
    const int lane  = threadIdx.x & 63;
    const int bm    = gwave >> 4;
    const int seg   = gwave & 15;
    const int b     = bm >> 7;

    const float* bx = boxes + bm * 7;
    const float cx = bx[0], cy = bx[1], czb = bx[2];
    const float dx = bx[3], dy = bx[4], dzv = bx[5], rz = bx[6];
    // fp32 reference semantics: no FMA contraction; trig via double → fp32
    const float cz   = __fadd_rn(czb, __fmul_rn(0.5f, dzv));
    const float cosa = (float)cos(-(double)rz);
    const float sina = (float)sin(-(double)rz);
    const float hdx = 0.5f * dx, hdy = 0.5f * dy, hdz = 0.5f * dzv;

    const float* pb = points + (size_t)b * N_ * 3;

    #pragma unroll 4
    for (int k = 0; k < 16; ++k) {
        const int chunk = seg * 16 + k;
        const int i = chunk * 64 + lane;
        const float x = pb[i*3+0], y = pb[i*3+1], z = pb[i*3+2];
        const float sx = __fsub_rn(x, cx);
        const float sy = __fsub_rn(y, cy);
        const float lx = __fsub_rn(__fmul_rn(sx, cosa), __fmul_rn(sy, sina));
        const float ly = __fadd_rn(__fmul_rn(sx, sina), __fmul_rn(sy, cosa));
        const bool pred = (fabsf(__fsub_rn(z, cz)) <= hdz) &&
                          (lx > -hdx) && (lx < hdx) &&
                          (ly > -hdy) && (ly < hdy);
        const unsigned long long m = __ballot(pred);
        if (lane == 0) {
            masks[(size_t)bm * NCHUNK_ + chunk] = m;
            cnts [(size_t)bm * NCHUNK_ + chunk] = __popcll(m);
        }
    }
}

// ---------------------------------------------------------------------------
// Fused resolve + pool: one block per box.
// 1) scan chunk counts, expand first min(cnt,S) in-box indices (ordered)
// 2) jtab[s] = s % cnt  (modulo hoisted out of the streaming loop)
// 3) stage up to TILE_ unique rows in LDS (feature float4s 16B-aligned)
// 4) stream the box's 512×131 floats as NT float4s (pure write stream;
//    duplicated rows come from LDS broadcast, not repeated global gathers)
// ---------------------------------------------------------------------------
__global__ __launch_bounds__(256) void pool_kernel(
    const float* __restrict__ points,        // (B, N, 3)
    const float* __restrict__ feats,         // (B, N, C)
    const unsigned long long* __restrict__ masks,
    const int* __restrict__ cnts,
    float* __restrict__ out,                 // (B, M, S, 131)
    float* __restrict__ flags_out)           // (B*M,)
{
    const int bm  = blockIdx.x;
    const int b   = bm >> 7;
    const int tid = threadIdx.x;

    __shared__ int   sc[NCHUNK_];
    __shared__ int   s_idx[S_];
    __shared__ int   jtab[S_];
    __shared__ float srow[TILE_ * RSTR_];    // 67.6 KB → 2 blocks/CU

    // --- scan ---
    const int c = cnts[(size_t)bm * NCHUNK_ + tid];
    sc[tid] = c;
    __syncthreads();
    for (int off = 1; off < NCHUNK_; off <<= 1) {
        const int v = (tid >= off) ? sc[tid - off] : 0;
        __syncthreads();
        sc[tid] += v;
        __syncthreads();
    }
    const int total = sc[NCHUNK_ - 1];
    const int P = sc[tid] - c;

    // --- expand ordered indices ---
    if (c > 0 && P < S_) {
        unsigned long long m = masks[(size_t)bm * NCHUNK_ + tid];
        int pos = P;
        while (m && pos < S_) {
            const int bit = __ffsll((unsigned long long)m) - 1;
            m &= m - 1;
            s_idx[pos++] = tid * 64 + bit;
        }
    }
    __syncthreads();

    const int cnt_eff = total < S_ ? total : S_;
    const int denom   = cnt_eff > 0 ? cnt_eff : 1;

    // --- wrap-around table ---
    for (int s = tid; s < S_; s += 256) jtab[s] = s % denom;

    // --- stage unique rows ---
    const int T = cnt_eff < TILE_ ? cnt_eff : TILE_;
    if (total == 0) {
        for (int e = tid; e < RSTR_; e += 256) srow[e] = 0.0f;  // row 0 zeros
    } else {
        // features: T*32 coalesced float4 loads (512 B rows, 16B-aligned LDS)
        const int nf4 = T * 32;
        for (int t = tid; t < nf4; t += 256) {
            const int u = t >> 5, q = t & 31;
            const size_t pbase = (size_t)b * N_ + (unsigned)s_idx[u];
            const f4_t v = *(const f4_t*)(feats + pbase * C_ + q * 4);
            *(f4_t*)(srow + u * RSTR_ + q * 4) = v;
        }
        // xyz: T*3 scalar loads
        for (int t = tid; t < T * 3; t += 256) {
            const int u = t / 3, k = t - u * 3;
            const size_t pbase = (size_t)b * N_ + (unsigned)s_idx[u];
            srow[u * RSTR_ + 128 + k] = points[pbase * 3 + k];
        }
    }
    __syncthreads();

    // --- stream output: 512*131 = 67072 floats = 16768 float4s (exact) ---
    float* ob = out + (size_t)bm * (S_ * ROW_);
    for (int f = tid; f < (S_ * ROW_) / 4; f += 256) {
        const int e = f * 4;
        f4_t v;
        #pragma unroll
        for (int jj = 0; jj < 4; ++jj) {
            const unsigned ee = (unsigned)(e + jj);
            const unsigned s  = ee / (unsigned)ROW_;   // magic-mul (const 131)
            const int col = (int)(ee - s * ROW_);
            const int j = jtab[s];
            float val;
            if (j < TILE_) {
                val = (col < 3) ? srow[j * RSTR_ + 128 + col]
                                : srow[j * RSTR_ + (col - 3)];
            } else {   // rare: cnt_eff > TILE_ → direct gather (L2 catches it)
                const size_t pbase = (size_t)b * N_ + (unsigned)s_idx[j];
                val = (col < 3) ? points[pbase * 3 + col]
                                : feats[pbase * C_ + (col - 3)];
            }
            v[jj] = val;
        }
        __builtin_nontemporal_store(v, (f4_t*)(ob + e));
    }
    if (tid == 0) flags_out[bm] = (total == 0) ? 1.0f : 0.0f;
}

extern "C" void kernel_launch(void* const* d_in, const int* in_sizes, int n_in,
                              void* d_out, int out_size, void* d_ws, size_t ws_size,
                              hipStream_t stream) {
    const float* points = (const float*)d_in[0];   // (B, N, 3)
    const float* feats  = (const float*)d_in[1];   // (B, N, C)
    const float* boxes  = (const float*)d_in[2];   // (B, M, 7)
    float* out = (float*)d_out;

    // Workspace: masks (1 MB) + cnts (0.5 MB)
    unsigned long long* masks = (unsigned long long*)d_ws;
    int* cnts = (int*)((char*)d_ws + (size_t)B_ * M_ * NCHUNK_ * 8);

    float* flags = out + (size_t)B_ * M_ * S_ * ROW_;

    // Phase A: 512 boxes × 16 wave-segments = 8192 waves = 2048 blocks
    mask_kernel<<<B_ * M_ * 16 / 4, 256, 0, stream>>>(points, boxes, masks, cnts);
    // Fused resolve + pool: one block per box
    pool_kernel<<<B_ * M_, 256, 0, stream>>>(points, feats, masks, cnts, out, flags);
}

// Round 5
// 187.235 us; speedup vs baseline: 1.4280x; 1.0746x over previous
//
#include <hip/hip_runtime.h>

// Problem constants (match reference)
#define B_ 4
#define N_ 16384
#define M_ 128
#define C_ 128
#define S_ 512
#define ROW_ 131           // 3 + C floats per pooled row
#define NCHUNK_ 256        // 64-point chunks per box (N_/64)
#define TILE_ 128          // unique rows staged in LDS per box
#define LSTR_ 136          // swizzled LDS row stride (floats)
#define KBOX_ 4            // boxes per wave in mask kernel

typedef float f4_t __attribute__((ext_vector_type(4)));

// Swizzled LDS address: for a fixed element-within-float4 slot, consecutive
// lanes (col += 4) land on consecutive banks -> conflict-free ds_read_b32.
// Injective for col in [0,131): (col&3)*34 + (col>>2) <= 3*34+32 = 134 < 136.
__device__ __forceinline__ int swz(int j, int col) {
    return j * LSTR_ + (col & 3) * 34 + (col >> 2);
}

// ---------------------------------------------------------------------------
// Phase A: per-(box, chunk) in-box bitmask via wave ballot.
// One wave holds 16 chunks (1024 points, 48 VGPRs) and tests them against
// KBOX_ consecutive boxes (same batch since 128 % KBOX_ == 0) — points are
// read once per 4 boxes instead of once per box.
// ---------------------------------------------------------------------------
__global__ __launch_bounds__(256) void mask_kernel(
    const float* __restrict__ points,        // (B, N, 3)
    const float* __restrict__ boxes,         // (B*M, 7)
    unsigned long long* __restrict__ masks,  // (B*M, NCHUNK_)
    int* __restrict__ cnts)                  // (B*M, NCHUNK_)
{
    const int gwave = blockIdx.x * 4 + (threadIdx.x >> 6);
    const int lane  = threadIdx.x & 63;
    const int grp   = gwave >> 4;            // box-group [0, B*M/KBOX_)
    const int seg   = gwave & 15;            // 16 chunks per segment
    const int bm0   = grp * KBOX_;
    const int b     = bm0 >> 7;              // batch (shared by the 4 boxes)

    const float* pb = points + (size_t)b * N_ * 3;
    float px[16], py[16], pz[16];
    #pragma unroll
    for (int k = 0; k < 16; ++k) {
        const int i = (seg * 16 + k) * 64 + lane;
        px[k] = pb[i*3+0]; py[k] = pb[i*3+1]; pz[k] = pb[i*3+2];
    }

    for (int kb = 0; kb < KBOX_; ++kb) {
        const int bm = bm0 + kb;
        const float* bx = boxes + bm * 7;
        const float cx = bx[0], cy = bx[1], czb = bx[2];
        const float dx = bx[3], dy = bx[4], dzv = bx[5], rz = bx[6];
        // fp32 reference semantics: no FMA contraction; trig via double->fp32
        const float cz   = __fadd_rn(czb, __fmul_rn(0.5f, dzv));
        const float cosa = (float)cos(-(double)rz);
        const float sina = (float)sin(-(double)rz);
        const float hdx = 0.5f * dx, hdy = 0.5f * dy, hdz = 0.5f * dzv;

        #pragma unroll
        for (int k = 0; k < 16; ++k) {
            const float sx = __fsub_rn(px[k], cx);
            const float sy = __fsub_rn(py[k], cy);
            const float lx = __fsub_rn(__fmul_rn(sx, cosa), __fmul_rn(sy, sina));
            const float ly = __fadd_rn(__fmul_rn(sx, sina), __fmul_rn(sy, cosa));
            const bool pred = (fabsf(__fsub_rn(pz[k], cz)) <= hdz) &&
                              (lx > -hdx) && (lx < hdx) &&
                              (ly > -hdy) && (ly < hdy);
            const unsigned long long m = __ballot(pred);
            if (lane == 0) {
                const int chunk = seg * 16 + k;
                masks[(size_t)bm * NCHUNK_ + chunk] = m;
                cnts [(size_t)bm * NCHUNK_ + chunk] = __popcll(m);
            }
        }
    }
}

// ---------------------------------------------------------------------------
// Fused resolve + pool: one block per box.
// scan counts -> expand first min(cnt,S) ordered indices -> jtab[s]=s%cnt ->
// stage up to TILE_ unique rows in swizzled LDS -> stream 512x131 floats as
// NT float4s (pure coalesced write stream; duplicates come from LDS).
// LDS: srow 69.6KB + sc/s_idx/jtab ~5.1KB = 74.8KB -> 2 blocks/CU.
// ---------------------------------------------------------------------------
__global__ __launch_bounds__(256) void pool_kernel(
    const float* __restrict__ points,        // (B, N, 3)
    const float* __restrict__ feats,         // (B, N, C)
    const unsigned long long* __restrict__ masks,
    const int* __restrict__ cnts,
    float* __restrict__ out,                 // (B, M, S, 131)
    float* __restrict__ flags_out)           // (B*M,)
{
    const int bm  = blockIdx.x;
    const int b   = bm >> 7;
    const int tid = threadIdx.x;

    __shared__ int   sc[NCHUNK_];
    __shared__ int   s_idx[S_];
    __shared__ int   jtab[S_ + 1];           // +1: streaming reads jtab[s0+1]
    __shared__ float srow[TILE_ * LSTR_];

    // --- scan chunk counts (Hillis–Steele, 8 rounds) ---
    const int c = cnts[(size_t)bm * NCHUNK_ + tid];
    sc[tid] = c;
    __syncthreads();
    for (int off = 1; off < NCHUNK_; off <<= 1) {
        const int v = (tid >= off) ? sc[tid - off] : 0;
        __syncthreads();
        sc[tid] += v;
        __syncthreads();
    }
    const int total = sc[NCHUNK_ - 1];
    const int P = sc[tid] - c;               // exclusive prefix (ordered)

    // --- expand ordered in-box indices ---
    if (c > 0 && P < S_) {
        unsigned long long m = masks[(size_t)bm * NCHUNK_ + tid];
        int pos = P;
        while (m && pos < S_) {
            const int bit = __ffsll((unsigned long long)m) - 1;
            m &= m - 1;
            s_idx[pos++] = tid * 64 + bit;
        }
    }
    __syncthreads();

    const int cnt_eff = total < S_ ? total : S_;
    const int denom   = cnt_eff > 0 ? cnt_eff : 1;
    for (int s = tid; s <= S_; s += 256) jtab[s] = (s < S_) ? (s % denom) : 0;

    // --- stage unique rows into swizzled LDS ---
    const int T = cnt_eff < TILE_ ? cnt_eff : TILE_;
    if (total == 0) {
        if (tid < LSTR_) srow[tid] = 0.0f;   // row 0 zeros (j is always 0)
    } else {
        const int nf4 = T * 32;              // 32 float4s of features per row
        for (int t = tid; t < nf4; t += 256) {
            const int u = t >> 5, q = t & 31;
            const size_t pbase = (size_t)b * N_ + (unsigned)s_idx[u];
            const f4_t v = *(const f4_t*)(feats + pbase * C_ + q * 4);
            #pragma unroll
            for (int jj = 0; jj < 4; ++jj)
                srow[swz(u, 3 + 4 * q + jj)] = v[jj];   // <=2-way: free
        }
        for (int t = tid; t < T * 3; t += 256) {
            const int u = t / 3, k = t - u * 3;
            const size_t pbase = (size_t)b * N_ + (unsigned)s_idx[u];
            srow[swz(u, k)] = points[pbase * 3 + k];
        }
    }
    __syncthreads();

    // --- stream output: 512*131 = 67072 floats = 16768 aligned float4s ---
    float* ob = out + (size_t)bm * (S_ * ROW_);
    for (int f = tid; f < (S_ * ROW_) / 4; f += 256) {
        const int e = 4 * f;
        const unsigned s0 = (unsigned)e / (unsigned)ROW_;  // magic-mul
        const int col0 = e - (int)s0 * ROW_;
        const int ja = jtab[s0], jb = jtab[s0 + 1];
        f4_t v;
        if ((ja < TILE_) & (jb < TILE_)) {   // common case: both rows staged
            #pragma unroll
            for (int jj = 0; jj < 4; ++jj) {
                int col = col0 + jj;
                const bool cross = col >= ROW_;
                col = cross ? col - ROW_ : col;
                const int j = cross ? jb : ja;
                v[jj] = srow[swz(j, col)];   // stride-1 banks: conflict-free
            }
        } else {                             // rare: cnt_eff > TILE_
            #pragma unroll
            for (int jj = 0; jj < 4; ++jj) {
                int col = col0 + jj;
                unsigned s = s0;
                if (col >= ROW_) { col -= ROW_; ++s; }
                const int j = jtab[s];
                float val;
                if (j < TILE_) {
                    val = srow[swz(j, col)];
                } else {
                    const size_t pbase = (size_t)b * N_ + (unsigned)s_idx[j];
                    val = (col < 3) ? points[pbase * 3 + col]
                                    : feats[pbase * C_ + (col - 3)];
                }
                v[jj] = val;
            }
        }
        __builtin_nontemporal_store(v, (f4_t*)(ob + e));
    }
    if (tid == 0) flags_out[bm] = (total == 0) ? 1.0f : 0.0f;
}

extern "C" void kernel_launch(void* const* d_in, const int* in_sizes, int n_in,
                              void* d_out, int out_size, void* d_ws, size_t ws_size,
                              hipStream_t stream) {
    const float* points = (const float*)d_in[0];   // (B, N, 3)
    const float* feats  = (const float*)d_in[1];   // (B, N, C)
    const float* boxes  = (const float*)d_in[2];   // (B, M, 7)
    float* out = (float*)d_out;

    // Workspace: masks (1 MB) + cnts (0.5 MB)
    unsigned long long* masks = (unsigned long long*)d_ws;
    int* cnts = (int*)((char*)d_ws + (size_t)B_ * M_ * NCHUNK_ * 8);

    float* flags = out + (size_t)B_ * M_ * S_ * ROW_;

    // Phase A: (512/KBOX_) box-groups x 16 segments = 2048 waves = 512 blocks
    mask_kernel<<<B_ * M_ * 16 / 4 / KBOX_, 256, 0, stream>>>(
        points, boxes, masks, cnts);
    // Fused resolve + pool: one block per box
    pool_kernel<<<B_ * M_, 256, 0, stream>>>(points, feats, masks, cnts, out, flags);
}